// Round 4
// baseline (180.169 us; speedup 1.0000x reference)
//
#include <hip/hip_runtime.h>
#include <hip/hip_bf16.h>

typedef unsigned short ushort_t;
using ushort4v = __attribute__((ext_vector_type(4))) ushort_t;
using ushort8 = __attribute__((ext_vector_type(8))) ushort_t;
using short8  = __attribute__((ext_vector_type(8))) short;
using float4v = __attribute__((ext_vector_type(4))) float;

#define Bsz 256
#define Aattr 32
#define Ddim 2048

__device__ __forceinline__ float bf2f(ushort_t u) {
    union { unsigned int i; float f; } c;
    c.i = ((unsigned int)u) << 16;
    return c.f;
}

__device__ __forceinline__ ushort_t f2bf(float f) {
    union { float f; unsigned int i; } c;
    c.f = f;
    unsigned int x = c.i;
    unsigned int r = (x + 0x7FFFu + ((x >> 16) & 1u)) >> 16;  // RNE
    return (ushort_t)r;
}

struct BfPair { ushort_t hi, lo; };

// split x into hi (bf16) + lo (bf16 of residual); x ~= hi + lo to ~2^-18 rel
__device__ __forceinline__ BfPair split_bf16(float x) {
    BfPair p;
    p.hi = f2bf(x);
    p.lo = f2bf(x - bf2f(p.hi));
    return p;
}

// ---------------------------------------------------------------------------
// Kernel 1: masked attribute reduction (fp32 in -> split bf16 hi/lo out)
//   s[b, d] = sum_a (label[b,a] > 0) * feat[b, a, d]
// grid (B, 2): block handles 1024 dims of one batch row; block-uniform mask
// branch skips ~half the 64 MB feat read.
// ---------------------------------------------------------------------------
__global__ __launch_bounds__(256) void k_reduce(
    const float* __restrict__ feat, const int* __restrict__ label,
    ushort_t* __restrict__ s_hi, ushort_t* __restrict__ s_lo) {
    const int b  = blockIdx.x;
    const int d0 = blockIdx.y * 1024 + threadIdx.x * 4;
    const float* fb = feat + (size_t)b * (Aattr * Ddim) + d0;
    const int* lb = label + b * Aattr;

    float acc0 = 0.f, acc1 = 0.f, acc2 = 0.f, acc3 = 0.f;
    for (int a = 0; a < Aattr; ++a) {
        if (lb[a] > 0) {  // block-uniform branch
            float4 v = *(const float4*)(fb + a * Ddim);
            acc0 += v.x; acc1 += v.y; acc2 += v.z; acc3 += v.w;
        }
    }
    ushort4v hi, lo;
    BfPair p0 = split_bf16(acc0); hi[0] = p0.hi; lo[0] = p0.lo;
    BfPair p1 = split_bf16(acc1); hi[1] = p1.hi; lo[1] = p1.lo;
    BfPair p2 = split_bf16(acc2); hi[2] = p2.hi; lo[2] = p2.lo;
    BfPair p3 = split_bf16(acc3); hi[3] = p3.hi; lo[3] = p3.lo;
    *(ushort4v*)(s_hi + (size_t)b * Ddim + d0) = hi;
    *(ushort4v*)(s_lo + (size_t)b * Ddim + d0) = lo;
}

// ---------------------------------------------------------------------------
// Kernel 2: fused transpose + split-downconvert:
//   W fp32 [d][e] -> WT_hi/WT_lo bf16 [e][d]
// 64x64 tiles; fp32 LDS tile padded to 65 cols: both the scalar write
// pattern and the strided read pattern land <=2 lanes/bank (free, m136).
// ---------------------------------------------------------------------------
__global__ __launch_bounds__(256) void k_wt(
    const float* __restrict__ W, ushort_t* __restrict__ WT_hi,
    ushort_t* __restrict__ WT_lo) {
    __shared__ float tile[64][65];
    const int bx = blockIdx.x;        // e-tile (cols of W)
    const int by = blockIdx.y;        // d-tile (rows of W)
    const int t  = threadIdx.x;

#pragma unroll
    for (int p = 0; p < 4; ++p) {
        const int row = p * 16 + (t >> 4);     // d within tile
        const int c   = (t & 15) * 4;          // e within tile
        float4 v = *(const float4*)(W + (size_t)(by * 64 + row) * Ddim + bx * 64 + c);
        tile[row][c + 0] = v.x;
        tile[row][c + 1] = v.y;
        tile[row][c + 2] = v.z;
        tile[row][c + 3] = v.w;
    }
    __syncthreads();
#pragma unroll
    for (int p = 0; p < 2; ++p) {
        const int er = p * 32 + (t >> 3);      // e within tile
        const int dc = (t & 7) * 8;            // d within tile
        ushort8 hi, lo;
#pragma unroll
        for (int j = 0; j < 8; ++j) {
            BfPair pr = split_bf16(tile[dc + j][er]);
            hi[j] = pr.hi; lo[j] = pr.lo;
        }
        const size_t off = (size_t)(bx * 64 + er) * Ddim + by * 64 + dc;
        *(ushort8*)(WT_hi + off) = hi;
        *(ushort8*)(WT_lo + off) = lo;
    }
}

// ---------------------------------------------------------------------------
// Kernel 3: out = tanh(s @ W + bias) with emulated-fp32 precision:
//   acc = S_hi*W_hi + S_hi*W_lo + S_lo*W_hi   (lo*lo dropped, ~2^-18 rel)
// mfma_f32_16x16x32_bf16; one wave/block; wave tile 32(m) x 64(n);
// operands straight from global (L2/L3-resident). Grid (8, 32).
// ---------------------------------------------------------------------------
__global__ __launch_bounds__(64) void k_gemm(
    const ushort_t* __restrict__ S_hi, const ushort_t* __restrict__ S_lo,
    const ushort_t* __restrict__ WT_hi, const ushort_t* __restrict__ WT_lo,
    const float* __restrict__ bias, float* __restrict__ out) {
    const int l    = threadIdx.x;
    const int quad = l >> 4;          // 0..3
    const int m16  = l & 15;
    const int m0   = blockIdx.x * 32;
    const int n0   = blockIdx.y * 64;

    float4v acc[2][4];
#pragma unroll
    for (int i = 0; i < 2; ++i)
#pragma unroll
        for (int j = 0; j < 4; ++j) acc[i][j] = {0.f, 0.f, 0.f, 0.f};

    // A-frag: lane holds A[m=m16][k=quad*8+j]; B-frag mirrored (n=m16).
    const size_t aoff = (size_t)(m0 + m16) * Ddim + quad * 8;
    const size_t boff = (size_t)(n0 + m16) * Ddim + quad * 8;
    const ushort_t* Ah0 = S_hi + aoff;
    const ushort_t* Al0 = S_lo + aoff;

    for (int k = 0; k < Ddim; k += 32) {
        short8 ah0 = *(const short8*)(Ah0 + k);
        short8 ah1 = *(const short8*)(Ah0 + 16 * Ddim + k);
        short8 al0 = *(const short8*)(Al0 + k);
        short8 al1 = *(const short8*)(Al0 + 16 * Ddim + k);
#pragma unroll
        for (int ni = 0; ni < 4; ++ni) {
            const size_t bo = boff + (size_t)(ni * 16) * Ddim + k;
            short8 bh = *(const short8*)(WT_hi + bo);
            short8 bl = *(const short8*)(WT_lo + bo);
            acc[0][ni] = __builtin_amdgcn_mfma_f32_16x16x32_bf16(ah0, bh, acc[0][ni], 0, 0, 0);
            acc[0][ni] = __builtin_amdgcn_mfma_f32_16x16x32_bf16(ah0, bl, acc[0][ni], 0, 0, 0);
            acc[0][ni] = __builtin_amdgcn_mfma_f32_16x16x32_bf16(al0, bh, acc[0][ni], 0, 0, 0);
            acc[1][ni] = __builtin_amdgcn_mfma_f32_16x16x32_bf16(ah1, bh, acc[1][ni], 0, 0, 0);
            acc[1][ni] = __builtin_amdgcn_mfma_f32_16x16x32_bf16(ah1, bl, acc[1][ni], 0, 0, 0);
            acc[1][ni] = __builtin_amdgcn_mfma_f32_16x16x32_bf16(al1, bh, acc[1][ni], 0, 0, 0);
        }
    }

    // C/D layout: col (n) = lane&15, row (m) = quad*4 + reg.
#pragma unroll
    for (int mi = 0; mi < 2; ++mi) {
#pragma unroll
        for (int ni = 0; ni < 4; ++ni) {
            const int n = n0 + ni * 16 + m16;
            const float bv = bias[n];
#pragma unroll
            for (int r = 0; r < 4; ++r) {
                const int m = m0 + mi * 16 + quad * 4 + r;
                out[(size_t)m * Ddim + n] = tanhf(acc[mi][ni][r] + bv);
            }
        }
    }
}

extern "C" void kernel_launch(void* const* d_in, const int* in_sizes, int n_in,
                              void* d_out, int out_size, void* d_ws, size_t ws_size,
                              hipStream_t stream) {
    // inputs (fp32 unless noted): x[256*2048] (dead for returned row),
    // feat[256*32*2048], label[256*32] (int32), W[2048*2048], b[2048]
    const float* feat  = (const float*)d_in[1];
    const int*   label = (const int*)d_in[2];
    const float* W     = (const float*)d_in[3];
    const float* bias  = (const float*)d_in[4];
    float*       out   = (float*)d_out;

    char* ws = (char*)d_ws;
    ushort_t* s_hi  = (ushort_t*)ws;                 // 1 MB
    ushort_t* s_lo  = (ushort_t*)(ws + (1u << 20));  // 1 MB
    ushort_t* WT_hi = (ushort_t*)(ws + (2u << 20));  // 8 MB
    ushort_t* WT_lo = (ushort_t*)(ws + (10u << 20)); // 8 MB

    k_reduce<<<dim3(Bsz, 2), dim3(256), 0, stream>>>(feat, label, s_hi, s_lo);
    k_wt<<<dim3(32, 32), dim3(256), 0, stream>>>(W, WT_hi, WT_lo);
    k_gemm<<<dim3(8, 32), dim3(64), 0, stream>>>(s_hi, s_lo, WT_hi, WT_lo, bias, out);
}

// Round 5
// 144.357 us; speedup vs baseline: 1.2481x; 1.2481x over previous
//
#include <hip/hip_runtime.h>
#include <hip/hip_bf16.h>

typedef unsigned short ushort_t;
using ushort4v = __attribute__((ext_vector_type(4))) ushort_t;
using ushort8 = __attribute__((ext_vector_type(8))) ushort_t;
using short8  = __attribute__((ext_vector_type(8))) short;
using float4v = __attribute__((ext_vector_type(4))) float;

#define Bsz 256
#define Aattr 32
#define Ddim 2048
#define OUTN (Bsz * Ddim)           // 524288 floats = 2 MB

__device__ __forceinline__ float bf2f(ushort_t u) {
    union { unsigned int i; float f; } c;
    c.i = ((unsigned int)u) << 16;
    return c.f;
}

__device__ __forceinline__ ushort_t f2bf(float f) {
    union { float f; unsigned int i; } c;
    c.f = f;
    unsigned int x = c.i;
    unsigned int r = (x + 0x7FFFu + ((x >> 16) & 1u)) >> 16;  // RNE
    return (ushort_t)r;
}

struct BfPair { ushort_t hi, lo; };
__device__ __forceinline__ BfPair split_bf16(float x) {
    BfPair p;
    p.hi = f2bf(x);
    p.lo = f2bf(x - bf2f(p.hi));
    return p;
}

// ---------------------------------------------------------------------------
// Kernel 1: masked attribute reduction (fp32 -> split bf16 hi/lo)
//   s[b,d] = sum_a (label[b,a] > 0) * feat[b,a,d]
// Active-index compaction (ballot+rank -> LDS) then unroll-4 main loop so
// the ~16 active float4 loads pipeline instead of load->wait->add serializing.
// grid (256 b, 2 half), 256 thr (8 waves/CU total occupancy).
// ---------------------------------------------------------------------------
__global__ __launch_bounds__(256) void k_reduce(
    const float* __restrict__ feat, const int* __restrict__ label,
    ushort_t* __restrict__ s_hi, ushort_t* __restrict__ s_lo) {
    __shared__ int list[Aattr];
    __shared__ int cnt;
    const int b = blockIdx.x;
    const int t = threadIdx.x;

    if (t < 64) {  // wave 0 builds the compacted active list
        int lab = label[b * Aattr + (t & 31)];
        unsigned long long vote = __ballot(lab > 0);
        unsigned m32 = (unsigned)(vote & 0xFFFFFFFFull);
        if (t < 32) {
            if (lab > 0) {
                int rank = __popc(m32 & ((1u << t) - 1u));
                list[rank] = t;
            }
            if (t == 0) cnt = __popc(m32);
        }
    }
    __syncthreads();

    const int n  = cnt;
    const int d0 = blockIdx.y * 1024 + t * 4;
    const float* fb = feat + (size_t)b * (Aattr * Ddim) + d0;

    float a0 = 0.f, a1 = 0.f, a2 = 0.f, a3 = 0.f;
    int i = 0;
    for (; i + 4 <= n; i += 4) {  // 4 independent loads per group
        const int j0 = list[i], j1 = list[i + 1], j2 = list[i + 2], j3 = list[i + 3];
        float4 v0 = *(const float4*)(fb + j0 * Ddim);
        float4 v1 = *(const float4*)(fb + j1 * Ddim);
        float4 v2 = *(const float4*)(fb + j2 * Ddim);
        float4 v3 = *(const float4*)(fb + j3 * Ddim);
        a0 += v0.x + v1.x + v2.x + v3.x;
        a1 += v0.y + v1.y + v2.y + v3.y;
        a2 += v0.z + v1.z + v2.z + v3.z;
        a3 += v0.w + v1.w + v2.w + v3.w;
    }
    for (; i < n; ++i) {
        float4 v = *(const float4*)(fb + list[i] * Ddim);
        a0 += v.x; a1 += v.y; a2 += v.z; a3 += v.w;
    }

    ushort4v hi, lo;
    BfPair p0 = split_bf16(a0); hi[0] = p0.hi; lo[0] = p0.lo;
    BfPair p1 = split_bf16(a1); hi[1] = p1.hi; lo[1] = p1.lo;
    BfPair p2 = split_bf16(a2); hi[2] = p2.hi; lo[2] = p2.lo;
    BfPair p3 = split_bf16(a3); hi[3] = p3.hi; lo[3] = p3.lo;
    *(ushort4v*)(s_hi + (size_t)b * Ddim + d0) = hi;
    *(ushort4v*)(s_lo + (size_t)b * Ddim + d0) = lo;
}

// ---------------------------------------------------------------------------
// Kernel 2: fused transpose + split-downconvert: W fp32 [d][e] -> WT hi/lo [e][d]
// 64x64 tiles; fp32 LDS tile padded to 65 (<=2-way bank aliasing = free).
// ---------------------------------------------------------------------------
__global__ __launch_bounds__(256) void k_wt(
    const float* __restrict__ W, ushort_t* __restrict__ WT_hi,
    ushort_t* __restrict__ WT_lo) {
    __shared__ float tile[64][65];
    const int bx = blockIdx.x;        // e-tile
    const int by = blockIdx.y;        // d-tile
    const int t  = threadIdx.x;

#pragma unroll
    for (int p = 0; p < 4; ++p) {
        const int row = p * 16 + (t >> 4);
        const int c   = (t & 15) * 4;
        float4 v = *(const float4*)(W + (size_t)(by * 64 + row) * Ddim + bx * 64 + c);
        tile[row][c + 0] = v.x;
        tile[row][c + 1] = v.y;
        tile[row][c + 2] = v.z;
        tile[row][c + 3] = v.w;
    }
    __syncthreads();
#pragma unroll
    for (int p = 0; p < 2; ++p) {
        const int er = p * 32 + (t >> 3);
        const int dc = (t & 7) * 8;
        ushort8 hi, lo;
#pragma unroll
        for (int j = 0; j < 8; ++j) {
            BfPair pr = split_bf16(tile[dc + j][er]);
            hi[j] = pr.hi; lo[j] = pr.lo;
        }
        const size_t off = (size_t)(bx * 64 + er) * Ddim + by * 64 + dc;
        *(ushort8*)(WT_hi + off) = hi;
        *(ushort8*)(WT_lo + off) = lo;
    }
}

// ---------------------------------------------------------------------------
// Kernel 3: K-split GEMM partials:
//   partials[ks][m][n] = sum_{k in chunk ks} emulated-fp32( S[m,k] * W[k,n] )
// One wave/block, wave tile 32(m) x 64(n). Grid: 256*KS blocks, 1-D.
// Swizzle: ks = g & (KS-1) so (with round-robin block->XCD dispatch) each XCD
// works one k-chunk -> its S-chunk + W-chunk stay L2-resident.
// ---------------------------------------------------------------------------
__global__ __launch_bounds__(64) void k_gemm(
    const ushort_t* __restrict__ S_hi, const ushort_t* __restrict__ S_lo,
    const ushort_t* __restrict__ WT_hi, const ushort_t* __restrict__ WT_lo,
    float* __restrict__ partials, int KS, int lks, int kchunk) {
    const int g    = blockIdx.x;
    const int ks   = g & (KS - 1);
    const int r    = g >> lks;
    const int m0   = (r & 7) * 32;
    const int n0   = (r >> 3) * 64;
    const int k0   = ks * kchunk;

    const int l    = threadIdx.x;
    const int quad = l >> 4;
    const int m16  = l & 15;

    float4v acc[2][4];
#pragma unroll
    for (int i = 0; i < 2; ++i)
#pragma unroll
        for (int j = 0; j < 4; ++j) acc[i][j] = {0.f, 0.f, 0.f, 0.f};

    // A-frag: lane holds A[m=m16][k=quad*8+j]; B-frag mirrored (n=m16).
    const size_t aoff = (size_t)(m0 + m16) * Ddim + quad * 8;
    const size_t boff = (size_t)(n0 + m16) * Ddim + quad * 8;
    const ushort_t* Ah = S_hi + aoff;
    const ushort_t* Al = S_lo + aoff;
    const ushort_t* Bh = WT_hi + boff;
    const ushort_t* Bl = WT_lo + boff;

#pragma unroll 2
    for (int k = k0; k < k0 + kchunk; k += 32) {
        // issue all 12 loads first so they pipeline
        short8 ah0 = *(const short8*)(Ah + k);
        short8 ah1 = *(const short8*)(Ah + 16 * Ddim + k);
        short8 al0 = *(const short8*)(Al + k);
        short8 al1 = *(const short8*)(Al + 16 * Ddim + k);
        short8 bh0 = *(const short8*)(Bh + k);
        short8 bh1 = *(const short8*)(Bh + 16 * Ddim + k);
        short8 bh2 = *(const short8*)(Bh + 32 * Ddim + k);
        short8 bh3 = *(const short8*)(Bh + 48 * Ddim + k);
        short8 bl0 = *(const short8*)(Bl + k);
        short8 bl1 = *(const short8*)(Bl + 16 * Ddim + k);
        short8 bl2 = *(const short8*)(Bl + 32 * Ddim + k);
        short8 bl3 = *(const short8*)(Bl + 48 * Ddim + k);

        acc[0][0] = __builtin_amdgcn_mfma_f32_16x16x32_bf16(ah0, bh0, acc[0][0], 0, 0, 0);
        acc[0][1] = __builtin_amdgcn_mfma_f32_16x16x32_bf16(ah0, bh1, acc[0][1], 0, 0, 0);
        acc[0][2] = __builtin_amdgcn_mfma_f32_16x16x32_bf16(ah0, bh2, acc[0][2], 0, 0, 0);
        acc[0][3] = __builtin_amdgcn_mfma_f32_16x16x32_bf16(ah0, bh3, acc[0][3], 0, 0, 0);
        acc[1][0] = __builtin_amdgcn_mfma_f32_16x16x32_bf16(ah1, bh0, acc[1][0], 0, 0, 0);
        acc[1][1] = __builtin_amdgcn_mfma_f32_16x16x32_bf16(ah1, bh1, acc[1][1], 0, 0, 0);
        acc[1][2] = __builtin_amdgcn_mfma_f32_16x16x32_bf16(ah1, bh2, acc[1][2], 0, 0, 0);
        acc[1][3] = __builtin_amdgcn_mfma_f32_16x16x32_bf16(ah1, bh3, acc[1][3], 0, 0, 0);

        acc[0][0] = __builtin_amdgcn_mfma_f32_16x16x32_bf16(ah0, bl0, acc[0][0], 0, 0, 0);
        acc[0][1] = __builtin_amdgcn_mfma_f32_16x16x32_bf16(ah0, bl1, acc[0][1], 0, 0, 0);
        acc[0][2] = __builtin_amdgcn_mfma_f32_16x16x32_bf16(ah0, bl2, acc[0][2], 0, 0, 0);
        acc[0][3] = __builtin_amdgcn_mfma_f32_16x16x32_bf16(ah0, bl3, acc[0][3], 0, 0, 0);
        acc[1][0] = __builtin_amdgcn_mfma_f32_16x16x32_bf16(ah1, bl0, acc[1][0], 0, 0, 0);
        acc[1][1] = __builtin_amdgcn_mfma_f32_16x16x32_bf16(ah1, bl1, acc[1][1], 0, 0, 0);
        acc[1][2] = __builtin_amdgcn_mfma_f32_16x16x32_bf16(ah1, bl2, acc[1][2], 0, 0, 0);
        acc[1][3] = __builtin_amdgcn_mfma_f32_16x16x32_bf16(ah1, bl3, acc[1][3], 0, 0, 0);

        acc[0][0] = __builtin_amdgcn_mfma_f32_16x16x32_bf16(al0, bh0, acc[0][0], 0, 0, 0);
        acc[0][1] = __builtin_amdgcn_mfma_f32_16x16x32_bf16(al0, bh1, acc[0][1], 0, 0, 0);
        acc[0][2] = __builtin_amdgcn_mfma_f32_16x16x32_bf16(al0, bh2, acc[0][2], 0, 0, 0);
        acc[0][3] = __builtin_amdgcn_mfma_f32_16x16x32_bf16(al0, bh3, acc[0][3], 0, 0, 0);
        acc[1][0] = __builtin_amdgcn_mfma_f32_16x16x32_bf16(al1, bh0, acc[1][0], 0, 0, 0);
        acc[1][1] = __builtin_amdgcn_mfma_f32_16x16x32_bf16(al1, bh1, acc[1][1], 0, 0, 0);
        acc[1][2] = __builtin_amdgcn_mfma_f32_16x16x32_bf16(al1, bh2, acc[1][2], 0, 0, 0);
        acc[1][3] = __builtin_amdgcn_mfma_f32_16x16x32_bf16(al1, bh3, acc[1][3], 0, 0, 0);
    }

    // C/D layout: col (n) = lane&15, row (m) = quad*4 + reg.
    float* pout = partials + (size_t)ks * OUTN;
#pragma unroll
    for (int mi = 0; mi < 2; ++mi) {
#pragma unroll
        for (int ni = 0; ni < 4; ++ni) {
            const int n = n0 + ni * 16 + m16;
#pragma unroll
            for (int rr = 0; rr < 4; ++rr) {
                const int m = m0 + mi * 16 + quad * 4 + rr;
                pout[(size_t)m * Ddim + n] = acc[mi][ni][rr];
            }
        }
    }
}

// ---------------------------------------------------------------------------
// Kernel 4: out = tanh(sum_ks partials + bias). 2 MB out, float4/thread.
// ---------------------------------------------------------------------------
__global__ __launch_bounds__(256) void k_finish(
    const float* __restrict__ partials, const float* __restrict__ bias,
    float* __restrict__ out, int KS) {
    const int i = (blockIdx.x * 256 + threadIdx.x) * 4;
    float a0 = 0.f, a1 = 0.f, a2 = 0.f, a3 = 0.f;
    for (int s = 0; s < KS; ++s) {
        float4 v = *(const float4*)(partials + (size_t)s * OUTN + i);
        a0 += v.x; a1 += v.y; a2 += v.z; a3 += v.w;
    }
    float4 bv = *(const float4*)(bias + (i & (Ddim - 1)));
    float4 o;
    o.x = tanhf(a0 + bv.x);
    o.y = tanhf(a1 + bv.y);
    o.z = tanhf(a2 + bv.z);
    o.w = tanhf(a3 + bv.w);
    *(float4*)(out + i) = o;
}

extern "C" void kernel_launch(void* const* d_in, const int* in_sizes, int n_in,
                              void* d_out, int out_size, void* d_ws, size_t ws_size,
                              hipStream_t stream) {
    // inputs (fp32 unless noted): x (dead for returned row), feat[256*32*2048],
    // label[256*32] (int32), W[2048*2048], b[2048]
    const float* feat  = (const float*)d_in[1];
    const int*   label = (const int*)d_in[2];
    const float* W     = (const float*)d_in[3];
    const float* bias  = (const float*)d_in[4];
    float*       out   = (float*)d_out;

    char* ws = (char*)d_ws;
    ushort_t* s_hi  = (ushort_t*)ws;                 // 1 MB
    ushort_t* s_lo  = (ushort_t*)(ws + (1u << 20));  // 1 MB
    ushort_t* WT_hi = (ushort_t*)(ws + (2u << 20));  // 8 MB
    ushort_t* WT_lo = (ushort_t*)(ws + (10u << 20)); // 8 MB
    float* partials = (float*)(ws + (18u << 20));    // KS * 2 MB

    // pick largest power-of-2 KS (<=8) whose partial slices fit in ws
    const size_t avail = ws_size > (18u << 20) ? ws_size - (18u << 20) : 0;
    int KS = 1, lks = 0;
    while (KS < 8 && (size_t)(KS * 2) * (OUTN * sizeof(float)) <= avail) { KS *= 2; ++lks; }
    const int kchunk = Ddim / KS;

    k_reduce<<<dim3(Bsz, 2), dim3(256), 0, stream>>>(feat, label, s_hi, s_lo);
    k_wt<<<dim3(32, 32), dim3(256), 0, stream>>>(W, WT_hi, WT_lo);
    k_gemm<<<dim3(256 * KS), dim3(64), 0, stream>>>(s_hi, s_lo, WT_hi, WT_lo,
                                                    partials, KS, lks, kchunk);
    k_finish<<<dim3(OUTN / 1024), dim3(256), 0, stream>>>(partials, bias, out, KS);
}

// Round 6
// 138.755 us; speedup vs baseline: 1.2985x; 1.0404x over previous
//
#include <hip/hip_runtime.h>
#include <hip/hip_bf16.h>

typedef unsigned short ushort_t;
using ushort4v = __attribute__((ext_vector_type(4))) ushort_t;
using ushort8 = __attribute__((ext_vector_type(8))) ushort_t;
using short8  = __attribute__((ext_vector_type(8))) short;
using float4v = __attribute__((ext_vector_type(4))) float;

#define Bsz 256
#define Aattr 32
#define Ddim 2048
#define OUTN (Bsz * Ddim)           // 524288 floats = 2 MB

__device__ __forceinline__ float bf2f(ushort_t u) {
    union { unsigned int i; float f; } c;
    c.i = ((unsigned int)u) << 16;
    return c.f;
}

__device__ __forceinline__ ushort_t f2bf(float f) {
    union { float f; unsigned int i; } c;
    c.f = f;
    unsigned int x = c.i;
    unsigned int r = (x + 0x7FFFu + ((x >> 16) & 1u)) >> 16;  // RNE
    return (ushort_t)r;
}

struct BfPair { ushort_t hi, lo; };
__device__ __forceinline__ BfPair split_bf16(float x) {
    BfPair p;
    p.hi = f2bf(x);
    p.lo = f2bf(x - bf2f(p.hi));
    return p;
}

// ---------------------------------------------------------------------------
// Kernel 1 (fused prep): two independent BW-bound jobs in one dispatch so
// their memory phases overlap.
//   blocks [0, 512):   masked attribute reduction -> s_hi/s_lo
//   blocks [512,1536): W fp32 [d][e] -> WT_hi/WT_lo bf16 [e][d] (64x64 tiles)
// ---------------------------------------------------------------------------
__global__ __launch_bounds__(256) void k_prep(
    const float* __restrict__ feat, const int* __restrict__ label,
    const float* __restrict__ W,
    ushort_t* __restrict__ s_hi, ushort_t* __restrict__ s_lo,
    ushort_t* __restrict__ WT_hi, ushort_t* __restrict__ WT_lo) {
    __shared__ float tile[64][65];   // wt path; reduce path reuses as int[]
    const int t = threadIdx.x;

    if (blockIdx.x < 512) {
        // ---- reduce path: b = id>>1, half = id&1 ----
        int* list = (int*)&tile[0][0];
        int* cntp = (int*)&tile[1][0];
        const int b    = blockIdx.x >> 1;
        const int half = blockIdx.x & 1;

        if (t < 64) {
            int lab = label[b * Aattr + (t & 31)];
            unsigned long long vote = __ballot(lab > 0);
            unsigned m32 = (unsigned)(vote & 0xFFFFFFFFull);
            if (t < 32) {
                if (lab > 0) {
                    int rank = __popc(m32 & ((1u << t) - 1u));
                    list[rank] = t;
                }
                if (t == 0) *cntp = __popc(m32);
            }
        }
        __syncthreads();

        const int n  = *cntp;
        const int d0 = half * 1024 + t * 4;
        const float* fb = feat + (size_t)b * (Aattr * Ddim) + d0;

        float a0 = 0.f, a1 = 0.f, a2 = 0.f, a3 = 0.f;
        int i = 0;
        for (; i + 4 <= n; i += 4) {
            const int j0 = list[i], j1 = list[i+1], j2 = list[i+2], j3 = list[i+3];
            float4 v0 = *(const float4*)(fb + j0 * Ddim);
            float4 v1 = *(const float4*)(fb + j1 * Ddim);
            float4 v2 = *(const float4*)(fb + j2 * Ddim);
            float4 v3 = *(const float4*)(fb + j3 * Ddim);
            a0 += v0.x + v1.x + v2.x + v3.x;
            a1 += v0.y + v1.y + v2.y + v3.y;
            a2 += v0.z + v1.z + v2.z + v3.z;
            a3 += v0.w + v1.w + v2.w + v3.w;
        }
        for (; i < n; ++i) {
            float4 v = *(const float4*)(fb + list[i] * Ddim);
            a0 += v.x; a1 += v.y; a2 += v.z; a3 += v.w;
        }

        ushort4v hi, lo;
        BfPair p0 = split_bf16(a0); hi[0] = p0.hi; lo[0] = p0.lo;
        BfPair p1 = split_bf16(a1); hi[1] = p1.hi; lo[1] = p1.lo;
        BfPair p2 = split_bf16(a2); hi[2] = p2.hi; lo[2] = p2.lo;
        BfPair p3 = split_bf16(a3); hi[3] = p3.hi; lo[3] = p3.lo;
        *(ushort4v*)(s_hi + (size_t)b * Ddim + d0) = hi;
        *(ushort4v*)(s_lo + (size_t)b * Ddim + d0) = lo;
    } else {
        // ---- transpose+split path: q = id-512; bx = q&31 (e-tile), by = q>>5 ----
        const int q  = blockIdx.x - 512;
        const int bx = q & 31;
        const int by = q >> 5;

#pragma unroll
        for (int p = 0; p < 4; ++p) {
            const int row = p * 16 + (t >> 4);
            const int c   = (t & 15) * 4;
            float4 v = *(const float4*)(W + (size_t)(by * 64 + row) * Ddim + bx * 64 + c);
            tile[row][c + 0] = v.x;
            tile[row][c + 1] = v.y;
            tile[row][c + 2] = v.z;
            tile[row][c + 3] = v.w;
        }
        __syncthreads();
#pragma unroll
        for (int p = 0; p < 2; ++p) {
            const int er = p * 32 + (t >> 3);
            const int dc = (t & 7) * 8;
            ushort8 hi, lo;
#pragma unroll
            for (int j = 0; j < 8; ++j) {
                BfPair pr = split_bf16(tile[dc + j][er]);
                hi[j] = pr.hi; lo[j] = pr.lo;
            }
            const size_t off = (size_t)(bx * 64 + er) * Ddim + by * 64 + dc;
            *(ushort8*)(WT_hi + off) = hi;
            *(ushort8*)(WT_lo + off) = lo;
        }
    }
}

// ---------------------------------------------------------------------------
// Kernel 2: K-split GEMM partials, wave tile 64(m) x 64(n):
//   partials[ks][m][n] = sum_{k in chunk ks} emu-fp32( S[m,k] * W[k,n] )
// 48 MFMA per k-step (hh, hl, lh), 16x16B loads batched at the top of each
// step so they pipeline under ~930 cyc of MFMA. Grid: 128 * KS one-wave
// blocks; ks = g & (KS-1) keeps each XCD on one L2-resident k-chunk.
// ---------------------------------------------------------------------------
__global__ __launch_bounds__(64) void k_gemm(
    const ushort_t* __restrict__ S_hi, const ushort_t* __restrict__ S_lo,
    const ushort_t* __restrict__ WT_hi, const ushort_t* __restrict__ WT_lo,
    float* __restrict__ partials, int KS, int lks, int kchunk) {
    const int g    = blockIdx.x;
    const int ks   = g & (KS - 1);
    const int r    = g >> lks;
    const int m0   = (r & 3) * 64;
    const int n0   = (r >> 2) * 64;
    const int k0   = ks * kchunk;

    const int l    = threadIdx.x;
    const int quad = l >> 4;
    const int m16  = l & 15;

    float4v acc[4][4];
#pragma unroll
    for (int i = 0; i < 4; ++i)
#pragma unroll
        for (int j = 0; j < 4; ++j) acc[i][j] = {0.f, 0.f, 0.f, 0.f};

    // A-frag: lane holds A[m=m16][k=quad*8+j]; B-frag mirrored (n=m16).
    const size_t aoff = (size_t)(m0 + m16) * Ddim + quad * 8;
    const size_t boff = (size_t)(n0 + m16) * Ddim + quad * 8;
    const ushort_t* Ah = S_hi + aoff;
    const ushort_t* Al = S_lo + aoff;
    const ushort_t* Bh = WT_hi + boff;
    const ushort_t* Bl = WT_lo + boff;

    for (int k = k0; k < k0 + kchunk; k += 32) {
        short8 ah[4], al[4], bh[4], bl[4];
#pragma unroll
        for (int i = 0; i < 4; ++i) {
            const size_t o = (size_t)(i * 16) * Ddim + k;
            ah[i] = *(const short8*)(Ah + o);
            al[i] = *(const short8*)(Al + o);
            bh[i] = *(const short8*)(Bh + o);
            bl[i] = *(const short8*)(Bl + o);
        }
#pragma unroll
        for (int mi = 0; mi < 4; ++mi) {
#pragma unroll
            for (int ni = 0; ni < 4; ++ni) {
                acc[mi][ni] = __builtin_amdgcn_mfma_f32_16x16x32_bf16(ah[mi], bh[ni], acc[mi][ni], 0, 0, 0);
                acc[mi][ni] = __builtin_amdgcn_mfma_f32_16x16x32_bf16(ah[mi], bl[ni], acc[mi][ni], 0, 0, 0);
                acc[mi][ni] = __builtin_amdgcn_mfma_f32_16x16x32_bf16(al[mi], bh[ni], acc[mi][ni], 0, 0, 0);
            }
        }
    }

    // C/D layout: col (n) = lane&15, row (m) = quad*4 + reg.
    float* pout = partials + (size_t)ks * OUTN;
#pragma unroll
    for (int mi = 0; mi < 4; ++mi) {
#pragma unroll
        for (int ni = 0; ni < 4; ++ni) {
            const int n = n0 + ni * 16 + m16;
#pragma unroll
            for (int rr = 0; rr < 4; ++rr) {
                const int m = m0 + mi * 16 + quad * 4 + rr;
                pout[(size_t)m * Ddim + n] = acc[mi][ni][rr];
            }
        }
    }
}

// ---------------------------------------------------------------------------
// Kernel 3: out = tanh(sum_ks partials + bias). float4/thread.
// ---------------------------------------------------------------------------
__global__ __launch_bounds__(256) void k_finish(
    const float* __restrict__ partials, const float* __restrict__ bias,
    float* __restrict__ out, int KS) {
    const int i = (blockIdx.x * 256 + threadIdx.x) * 4;
    float a0 = 0.f, a1 = 0.f, a2 = 0.f, a3 = 0.f;
    for (int s = 0; s < KS; ++s) {
        float4 v = *(const float4*)(partials + (size_t)s * OUTN + i);
        a0 += v.x; a1 += v.y; a2 += v.z; a3 += v.w;
    }
    float4 bv = *(const float4*)(bias + (i & (Ddim - 1)));
    float4 o;
    o.x = tanhf(a0 + bv.x);
    o.y = tanhf(a1 + bv.y);
    o.z = tanhf(a2 + bv.z);
    o.w = tanhf(a3 + bv.w);
    *(float4*)(out + i) = o;
}

extern "C" void kernel_launch(void* const* d_in, const int* in_sizes, int n_in,
                              void* d_out, int out_size, void* d_ws, size_t ws_size,
                              hipStream_t stream) {
    // inputs (fp32 unless noted): x (dead for returned row), feat[256*32*2048],
    // label[256*32] (int32), W[2048*2048], b[2048]
    const float* feat  = (const float*)d_in[1];
    const int*   label = (const int*)d_in[2];
    const float* W     = (const float*)d_in[3];
    const float* bias  = (const float*)d_in[4];
    float*       out   = (float*)d_out;

    char* ws = (char*)d_ws;
    ushort_t* s_hi  = (ushort_t*)ws;                 // 1 MB
    ushort_t* s_lo  = (ushort_t*)(ws + (1u << 20));  // 1 MB
    ushort_t* WT_hi = (ushort_t*)(ws + (2u << 20));  // 8 MB
    ushort_t* WT_lo = (ushort_t*)(ws + (10u << 20)); // 8 MB
    float* partials = (float*)(ws + (18u << 20));    // KS * 2 MB

    // largest power-of-2 KS (<=8) whose partial slices fit in ws
    const size_t avail = ws_size > (18u << 20) ? ws_size - (18u << 20) : 0;
    int KS = 1, lks = 0;
    while (KS < 8 && (size_t)(KS * 2) * (OUTN * sizeof(float)) <= avail) { KS *= 2; ++lks; }
    const int kchunk = Ddim / KS;

    k_prep<<<dim3(1536), dim3(256), 0, stream>>>(feat, label, W, s_hi, s_lo, WT_hi, WT_lo);
    k_gemm<<<dim3(128 * KS), dim3(64), 0, stream>>>(s_hi, s_lo, WT_hi, WT_lo,
                                                    partials, KS, lks, kchunk);
    k_finish<<<dim3(OUTN / 1024), dim3(256), 0, stream>>>(partials, bias, out, KS);
}

// Round 7
// 137.631 us; speedup vs baseline: 1.3091x; 1.0082x over previous
//
#include <hip/hip_runtime.h>
#include <hip/hip_bf16.h>

typedef unsigned short ushort_t;
using ushort4v = __attribute__((ext_vector_type(4))) ushort_t;
using ushort8 = __attribute__((ext_vector_type(8))) ushort_t;
using short8  = __attribute__((ext_vector_type(8))) short;
using float4v = __attribute__((ext_vector_type(4))) float;

#define Bsz 256
#define Aattr 32
#define Ddim 2048

__device__ __forceinline__ float bf2f(ushort_t u) {
    union { unsigned int i; float f; } c;
    c.i = ((unsigned int)u) << 16;
    return c.f;
}

__device__ __forceinline__ ushort_t f2bf(float f) {
    union { float f; unsigned int i; } c;
    c.f = f;
    unsigned int x = c.i;
    unsigned int r = (x + 0x7FFFu + ((x >> 16) & 1u)) >> 16;  // RNE
    return (ushort_t)r;
}

struct BfPair { ushort_t hi, lo; };
__device__ __forceinline__ BfPair split_bf16(float x) {
    BfPair p;
    p.hi = f2bf(x);
    p.lo = f2bf(x - bf2f(p.hi));
    return p;
}

// ---------------------------------------------------------------------------
// Kernel 1 (fused prep): two independent BW-bound jobs in one dispatch.
//   blocks [0, 512):   masked attribute reduction -> s_hi/s_lo
//   blocks [512,1536): W fp32 [d][e] -> WT_hi/WT_lo bf16 [e][d] (64x64 tiles)
// ---------------------------------------------------------------------------
__global__ __launch_bounds__(256) void k_prep(
    const float* __restrict__ feat, const int* __restrict__ label,
    const float* __restrict__ W,
    ushort_t* __restrict__ s_hi, ushort_t* __restrict__ s_lo,
    ushort_t* __restrict__ WT_hi, ushort_t* __restrict__ WT_lo) {
    __shared__ float tile[64][65];   // wt path; reduce path reuses as int[]
    const int t = threadIdx.x;

    if (blockIdx.x < 512) {
        // ---- reduce path: b = id>>1, half = id&1 ----
        int* list = (int*)&tile[0][0];
        int* cntp = (int*)&tile[1][0];
        const int b    = blockIdx.x >> 1;
        const int half = blockIdx.x & 1;

        if (t < 64) {
            int lab = label[b * Aattr + (t & 31)];
            unsigned long long vote = __ballot(lab > 0);
            unsigned m32 = (unsigned)(vote & 0xFFFFFFFFull);
            if (t < 32) {
                if (lab > 0) {
                    int rank = __popc(m32 & ((1u << t) - 1u));
                    list[rank] = t;
                }
                if (t == 0) *cntp = __popc(m32);
            }
        }
        __syncthreads();

        const int n  = *cntp;
        const int d0 = half * 1024 + t * 4;
        const float* fb = feat + (size_t)b * (Aattr * Ddim) + d0;

        float a0 = 0.f, a1 = 0.f, a2 = 0.f, a3 = 0.f;
        int i = 0;
        for (; i + 4 <= n; i += 4) {
            const int j0 = list[i], j1 = list[i+1], j2 = list[i+2], j3 = list[i+3];
            float4 v0 = *(const float4*)(fb + j0 * Ddim);
            float4 v1 = *(const float4*)(fb + j1 * Ddim);
            float4 v2 = *(const float4*)(fb + j2 * Ddim);
            float4 v3 = *(const float4*)(fb + j3 * Ddim);
            a0 += v0.x + v1.x + v2.x + v3.x;
            a1 += v0.y + v1.y + v2.y + v3.y;
            a2 += v0.z + v1.z + v2.z + v3.z;
            a3 += v0.w + v1.w + v2.w + v3.w;
        }
        for (; i < n; ++i) {
            float4 v = *(const float4*)(fb + list[i] * Ddim);
            a0 += v.x; a1 += v.y; a2 += v.z; a3 += v.w;
        }

        ushort4v hi, lo;
        BfPair p0 = split_bf16(a0); hi[0] = p0.hi; lo[0] = p0.lo;
        BfPair p1 = split_bf16(a1); hi[1] = p1.hi; lo[1] = p1.lo;
        BfPair p2 = split_bf16(a2); hi[2] = p2.hi; lo[2] = p2.lo;
        BfPair p3 = split_bf16(a3); hi[3] = p3.hi; lo[3] = p3.lo;
        *(ushort4v*)(s_hi + (size_t)b * Ddim + d0) = hi;
        *(ushort4v*)(s_lo + (size_t)b * Ddim + d0) = lo;
    } else {
        // ---- transpose+split path ----
        const int q  = blockIdx.x - 512;
        const int bx = q & 31;        // e-tile
        const int by = q >> 5;        // d-tile

#pragma unroll
        for (int p = 0; p < 4; ++p) {
            const int row = p * 16 + (t >> 4);
            const int c   = (t & 15) * 4;
            float4 v = *(const float4*)(W + (size_t)(by * 64 + row) * Ddim + bx * 64 + c);
            tile[row][c + 0] = v.x;
            tile[row][c + 1] = v.y;
            tile[row][c + 2] = v.z;
            tile[row][c + 3] = v.w;
        }
        __syncthreads();
#pragma unroll
        for (int p = 0; p < 2; ++p) {
            const int er = p * 32 + (t >> 3);
            const int dc = (t & 7) * 8;
            ushort8 hi, lo;
#pragma unroll
            for (int j = 0; j < 8; ++j) {
                BfPair pr = split_bf16(tile[dc + j][er]);
                hi[j] = pr.hi; lo[j] = pr.lo;
            }
            const size_t off = (size_t)(bx * 64 + er) * Ddim + by * 64 + dc;
            *(ushort8*)(WT_hi + off) = hi;
            *(ushort8*)(WT_lo + off) = lo;
        }
    }
}

// ---------------------------------------------------------------------------
// Kernel 2: fused GEMM + K-reduce + bias + tanh.
// 256 blocks x 4 waves. Block owns a 32(m) x 64(n) tile of out; wave w
// accumulates K-chunk [w*512, (w+1)*512) with emulated-fp32 (hh+hl+lh MFMA),
// then waves reduce through LDS and the block applies bias+tanh, storing
// fp32 out directly (no partials round-trip, no 3rd kernel).
// Swizzle: n_tile=(g&7)*4+(g>>6), m_tile=(g>>3)&7 -> with round-robin
// block->XCD dispatch each XCD reads S (2 MB) + a 2 MB WT slice ~= its L2.
// ---------------------------------------------------------------------------
__global__ __launch_bounds__(256) void k_gemm2(
    const ushort_t* __restrict__ S_hi, const ushort_t* __restrict__ S_lo,
    const ushort_t* __restrict__ WT_hi, const ushort_t* __restrict__ WT_lo,
    const float* __restrict__ bias, float* __restrict__ out) {
    __shared__ float red[4][32 * 64];

    const int g      = blockIdx.x;
    const int n_tile = (g & 7) * 4 + (g >> 6);
    const int m_tile = (g >> 3) & 7;
    const int m0     = m_tile * 32;
    const int n0     = n_tile * 64;

    const int t    = threadIdx.x;
    const int w    = t >> 6;          // wave id 0..3
    const int l    = t & 63;
    const int quad = l >> 4;
    const int m16  = l & 15;
    const int k0   = w * 512;

    float4v acc[2][4];
#pragma unroll
    for (int i = 0; i < 2; ++i)
#pragma unroll
        for (int j = 0; j < 4; ++j) acc[i][j] = {0.f, 0.f, 0.f, 0.f};

    // A-frag: lane holds A[m=m16][k=quad*8+j]; B-frag mirrored (n=m16).
    const size_t aoff = (size_t)(m0 + m16) * Ddim + quad * 8;
    const size_t boff = (size_t)(n0 + m16) * Ddim + quad * 8;
    const ushort_t* Ah = S_hi + aoff;
    const ushort_t* Al = S_lo + aoff;
    const ushort_t* Bh = WT_hi + boff;
    const ushort_t* Bl = WT_lo + boff;

    for (int k = k0; k < k0 + 512; k += 32) {
        short8 ah0 = *(const short8*)(Ah + k);
        short8 ah1 = *(const short8*)(Ah + 16 * Ddim + k);
        short8 al0 = *(const short8*)(Al + k);
        short8 al1 = *(const short8*)(Al + 16 * Ddim + k);
        short8 bh[4], bl[4];
#pragma unroll
        for (int i = 0; i < 4; ++i) {
            const size_t o = (size_t)(i * 16) * Ddim + k;
            bh[i] = *(const short8*)(Bh + o);
            bl[i] = *(const short8*)(Bl + o);
        }
#pragma unroll
        for (int ni = 0; ni < 4; ++ni) {
            acc[0][ni] = __builtin_amdgcn_mfma_f32_16x16x32_bf16(ah0, bh[ni], acc[0][ni], 0, 0, 0);
            acc[0][ni] = __builtin_amdgcn_mfma_f32_16x16x32_bf16(ah0, bl[ni], acc[0][ni], 0, 0, 0);
            acc[0][ni] = __builtin_amdgcn_mfma_f32_16x16x32_bf16(al0, bh[ni], acc[0][ni], 0, 0, 0);
            acc[1][ni] = __builtin_amdgcn_mfma_f32_16x16x32_bf16(ah1, bh[ni], acc[1][ni], 0, 0, 0);
            acc[1][ni] = __builtin_amdgcn_mfma_f32_16x16x32_bf16(ah1, bl[ni], acc[1][ni], 0, 0, 0);
            acc[1][ni] = __builtin_amdgcn_mfma_f32_16x16x32_bf16(al1, bh[ni], acc[1][ni], 0, 0, 0);
        }
    }

    // dump wave tiles to LDS (C/D layout: col(n)=lane&15, row(m)=quad*4+reg)
#pragma unroll
    for (int mi = 0; mi < 2; ++mi) {
#pragma unroll
        for (int ni = 0; ni < 4; ++ni) {
#pragma unroll
            for (int rr = 0; rr < 4; ++rr) {
                red[w][(mi * 16 + quad * 4 + rr) * 64 + ni * 16 + m16] = acc[mi][ni][rr];
            }
        }
    }
    __syncthreads();

    // reduce 4 waves + bias + tanh; thread t -> m_l = t>>3, n_l = (t&7)*8
    const int m_l = t >> 3;
    const int n_l = (t & 7) * 8;
    const int base = m_l * 64 + n_l;
    float s[8];
#pragma unroll
    for (int j = 0; j < 8; ++j) s[j] = 0.f;
#pragma unroll
    for (int ww = 0; ww < 4; ++ww) {
        float4 v0 = *(const float4*)&red[ww][base];
        float4 v1 = *(const float4*)&red[ww][base + 4];
        s[0] += v0.x; s[1] += v0.y; s[2] += v0.z; s[3] += v0.w;
        s[4] += v1.x; s[5] += v1.y; s[6] += v1.z; s[7] += v1.w;
    }
    float4 b0 = *(const float4*)(bias + n0 + n_l);
    float4 b1 = *(const float4*)(bias + n0 + n_l + 4);
    float4 o0, o1;
    o0.x = tanhf(s[0] + b0.x);
    o0.y = tanhf(s[1] + b0.y);
    o0.z = tanhf(s[2] + b0.z);
    o0.w = tanhf(s[3] + b0.w);
    o1.x = tanhf(s[4] + b1.x);
    o1.y = tanhf(s[5] + b1.y);
    o1.z = tanhf(s[6] + b1.z);
    o1.w = tanhf(s[7] + b1.w);
    float* op = out + (size_t)(m0 + m_l) * Ddim + n0 + n_l;
    *(float4*)op = o0;
    *(float4*)(op + 4) = o1;
}

extern "C" void kernel_launch(void* const* d_in, const int* in_sizes, int n_in,
                              void* d_out, int out_size, void* d_ws, size_t ws_size,
                              hipStream_t stream) {
    // inputs (fp32 unless noted): x (dead for returned row), feat[256*32*2048],
    // label[256*32] (int32), W[2048*2048], b[2048]
    const float* feat  = (const float*)d_in[1];
    const int*   label = (const int*)d_in[2];
    const float* W     = (const float*)d_in[3];
    const float* bias  = (const float*)d_in[4];
    float*       out   = (float*)d_out;

    char* ws = (char*)d_ws;
    ushort_t* s_hi  = (ushort_t*)ws;                 // 1 MB
    ushort_t* s_lo  = (ushort_t*)(ws + (1u << 20));  // 1 MB
    ushort_t* WT_hi = (ushort_t*)(ws + (2u << 20));  // 8 MB
    ushort_t* WT_lo = (ushort_t*)(ws + (10u << 20)); // 8 MB

    k_prep<<<dim3(1536), dim3(256), 0, stream>>>(feat, label, W, s_hi, s_lo, WT_hi, WT_lo);
    k_gemm2<<<dim3(256), dim3(256), 0, stream>>>(s_hi, s_lo, WT_hi, WT_lo, bias, out);
}